// Round 8
// baseline (371.783 us; speedup 1.0000x reference)
//
#include <hip/hip_runtime.h>
#include <hip/hip_bf16.h>

#define BSZ 4
#define NN  256
#define DXX 256
#define DEE 64
#define DYY 64

// ---- workspace layout (float offsets) ----
#define OFF_Q     0          // 262144  (row-major [b][i][c])
#define OFF_K     262144     // 262144  (TRANSPOSED: [b][c][j])
#define OFF_V     524288     // 262144  (TRANSPOSED: [b][c][j])
#define OFF_XW    786432     // 262144
#define OFF_YE1   1048576    // 1024
#define OFF_YE2   1049600    // 1024
#define OFF_YX1   1050624    // 1024
#define OFF_YX2   1051648    // 1024
#define OFF_PX    1052672    // 4096
#define OFF_EPART 1057792    // 65536

typedef __attribute__((ext_vector_type(8))) short bf16x8;
typedef __attribute__((ext_vector_type(4))) float f32x4;

__device__ __forceinline__ short f2bf(float f) {
    unsigned u = __float_as_uint(f);
    unsigned r = u + 0x7fffu + ((u >> 16) & 1u);
    return (short)(r >> 16);
}

// packed f32x2 -> bf16x2 (RTNE), 1 VALU op per 2 values (no builtin on gfx950)
__device__ __forceinline__ unsigned cvt_pk_bf16(float lo, float hi) {
    unsigned r;
    asm("v_cvt_pk_bf16_f32 %0, %1, %2" : "=v"(r) : "v"(lo), "v"(hi));
    return r;
}

__device__ __forceinline__ void pack8_store(const float4& A, const float4& B, short* dst) {
    uint4 v;
    v.x = cvt_pk_bf16(A.x, A.y);
    v.y = cvt_pk_bf16(A.z, A.w);
    v.z = cvt_pk_bf16(B.x, B.y);
    v.w = cvt_pk_bf16(B.z, B.w);
    *(uint4*)dst = v;
}

// ================= PREP: qkv (192 blocks) + yproj (4) + epoolA (256) + xpool (4) =================
__global__ __launch_bounds__(256) void prep_kernel(
    const float* __restrict__ x, const float* __restrict__ e, const float* __restrict__ y,
    const float* __restrict__ nm,
    const float* __restrict__ Wq, const float* __restrict__ Wk, const float* __restrict__ Wv,
    const float* __restrict__ Wye_add, const float* __restrict__ Wye_mul,
    const float* __restrict__ Wyx_add, const float* __restrict__ Wyx_mul,
    float* __restrict__ ws) {

    __shared__ float smem[16 * 256];
    const int blk = blockIdx.x;
    const int t = threadIdx.x;

    if (blk < 192) {
        const int m0 = (blk & 63) * 16;
        const int which = blk >> 6;
        const float* W = which == 0 ? Wq : (which == 1 ? Wk : Wv);
        float* out = ws + (size_t)which * 262144;
        float (*xl)[256] = (float(*)[256])smem;
        for (int r = 0; r < 16; ++r) xl[r][t] = x[(m0 + r) * 256 + t];
        __syncthreads();
        float acc[16];
#pragma unroll
        for (int r = 0; r < 16; ++r) acc[r] = 0.f;
        for (int d = 0; d < 256; d += 4) {
            float w0 = W[(d + 0) * 256 + t];
            float w1 = W[(d + 1) * 256 + t];
            float w2 = W[(d + 2) * 256 + t];
            float w3 = W[(d + 3) * 256 + t];
#pragma unroll
            for (int r = 0; r < 16; ++r) {
                float4 ev = *(const float4*)&xl[r][d];
                acc[r] = fmaf(ev.x, w0, fmaf(ev.y, w1, fmaf(ev.z, w2, fmaf(ev.w, w3, acc[r]))));
            }
        }
        if (which == 0) {
            // Q stays row-major [b][i][c]  (m = b*256+i is the global row)
#pragma unroll
            for (int r = 0; r < 16; ++r) {
                int m = m0 + r;
                out[m * 256 + t] = acc[r] * nm[m];
            }
        } else {
            // K,V stored TRANSPOSED [b][c][j]: decompose m0 = b*256 + jloc.
            const int bb2  = m0 >> 8;        // batch (16 rows never straddle a batch)
            const int jloc = m0 & 255;       // j within batch
            float tv[16];
#pragma unroll
            for (int r = 0; r < 16; ++r) tv[r] = acc[r] * nm[m0 + r];
            float* outb = out + (size_t)bb2 * 65536 + t * 256 + jloc;
#pragma unroll
            for (int g = 0; g < 4; ++g)
                *(float4*)&outb[g * 4] =
                    make_float4(tv[4 * g], tv[4 * g + 1], tv[4 * g + 2], tv[4 * g + 3]);
        }
    } else if (blk < 196) {
        const int b = blk - 192;
        float a1 = 0.f, a2 = 0.f, a3 = 0.f, a4 = 0.f;
        for (int k = 0; k < DYY; ++k) {
            float yv = y[b * DYY + k];
            a1 = fmaf(yv, Wye_add[k * 256 + t], a1);
            a2 = fmaf(yv, Wye_mul[k * 256 + t], a2);
            a3 = fmaf(yv, Wyx_add[k * 256 + t], a3);
            a4 = fmaf(yv, Wyx_mul[k * 256 + t], a4);
        }
        ws[OFF_YE1 + b * 256 + t] = a1;
        ws[OFF_YE2 + b * 256 + t] = a2;
        ws[OFF_YX1 + b * 256 + t] = a3;
        ws[OFF_YX2 + b * 256 + t] = a4;
    } else if (blk < 452) {
        // e-pool partials: float4 loads
        const int idx = blk - 196;
        const int s = idx & 63, bb = idx >> 6;
        const int dq = (t & 15) * 4, g = t >> 4;
        const float* base = e + ((size_t)bb * 65536 + s * 1024) * 64;
        float s0 = 0.f, s1 = 0.f, s2 = 0.f, s3 = 0.f;
        float q0 = 0.f, q1 = 0.f, q2 = 0.f, q3 = 0.f;
        float mn0 = 1e30f, mn1 = 1e30f, mn2 = 1e30f, mn3 = 1e30f;
        float mx0 = -1e30f, mx1 = -1e30f, mx2 = -1e30f, mx3 = -1e30f;
#pragma unroll 4
        for (int rr = 0; rr < 64; ++rr) {
            const int row = g * 64 + rr;
            float4 v = *(const float4*)&base[row * 64 + dq];
            s0 += v.x; s1 += v.y; s2 += v.z; s3 += v.w;
            q0 = fmaf(v.x, v.x, q0); q1 = fmaf(v.y, v.y, q1);
            q2 = fmaf(v.z, v.z, q2); q3 = fmaf(v.w, v.w, q3);
            mn0 = fminf(mn0, v.x); mn1 = fminf(mn1, v.y);
            mn2 = fminf(mn2, v.z); mn3 = fminf(mn3, v.w);
            mx0 = fmaxf(mx0, v.x); mx1 = fmaxf(mx1, v.y);
            mx2 = fmaxf(mx2, v.z); mx3 = fmaxf(mx3, v.w);
        }
        float (*red)[16][64] = (float(*)[16][64])smem;
        red[0][g][dq + 0] = s0;  red[0][g][dq + 1] = s1;  red[0][g][dq + 2] = s2;  red[0][g][dq + 3] = s3;
        red[1][g][dq + 0] = q0;  red[1][g][dq + 1] = q1;  red[1][g][dq + 2] = q2;  red[1][g][dq + 3] = q3;
        red[2][g][dq + 0] = mn0; red[2][g][dq + 1] = mn1; red[2][g][dq + 2] = mn2; red[2][g][dq + 3] = mn3;
        red[3][g][dq + 0] = mx0; red[3][g][dq + 1] = mx1; red[3][g][dq + 2] = mx2; red[3][g][dq + 3] = mx3;
        __syncthreads();
        const int stat = t >> 6, d = t & 63;
        float a;
        if (stat < 2) {
            a = 0.f;
            for (int gg = 0; gg < 16; ++gg) a += red[stat][gg][d];
        } else if (stat == 2) {
            a = 1e30f;
            for (int gg = 0; gg < 16; ++gg) a = fminf(a, red[2][gg][d]);
        } else {
            a = -1e30f;
            for (int gg = 0; gg < 16; ++gg) a = fmaxf(a, red[3][gg][d]);
        }
        ws[OFF_EPART + (size_t)((bb * 64 + s) * 64 + d) * 4 + stat] = a;
    } else {
        const int b = blk - 452;
        float s = 0.f, q = 0.f, mn = 1e30f, mx = -1e30f;
        for (int i = 0; i < 256; ++i) {
            float v = x[(b * 256 + i) * 256 + t];
            s += v; q = fmaf(v, v, q);
            mn = fminf(mn, v); mx = fmaxf(mx, v);
        }
        float mean = s * (1.f / 256.f);
        float var  = (q - s * s * (1.f / 256.f)) * (1.f / 255.f);
        var = fmaxf(var, 0.f);
        ws[OFF_PX + b * 1024 + t]       = mean;
        ws[OFF_PX + b * 1024 + 256 + t] = mn;
        ws[OFF_PX + b * 1024 + 512 + t] = mx;
        ws[OFF_PX + b * 1024 + 768 + t] = sqrtf(var);
    }
}

// ================= FUSED: E1/E2 (MFMA) + Y + online softmax + newE (MFMA) + xw =================
// ONE barrier per chunk (see R7). R8: __launch_bounds__(256,3) — R7 measured VGPR=112,
// LDS=44032B; 3 blocks/CU fits (VGPR cap at 3 waves/EU ~168 > 112; LDS 3*44032=129KB<160KB).
// R7 occupancy was pinned at 2 blocks/CU (20.6%) purely by the (256,2) annotation while
// MfmaUtil=10.7/VALUBusy=38 show ~50% idle-issue — more resident blocks overlap the stalls.
// (Historical "(256,3) spills" applied when weight-frag demand was >168; demand is 112 now.)
#define EBP  72
#define YPLP 264

__global__ __launch_bounds__(256, 3) void fusedmfma_kernel(
    const float* __restrict__ e, const float* __restrict__ nmask,
    const float* __restrict__ Wm, const float* __restrict__ Wa,
    const float* __restrict__ We_out, const float* __restrict__ be_out,
    const float* __restrict__ ws, float* __restrict__ outE, float* __restrict__ xw) {

    const int i = blockIdx.x, b = blockIdx.y;
    const int tid  = threadIdx.x;
    const int w    = tid >> 6;
    const int lane = tid & 63;
    const int quad = lane >> 4, l16 = lane & 15;

    __shared__ __align__(16) short ebuf[2][32 * EBP];   //  9216 B
    __shared__ __align__(16) short ypl[2][32 * YPLP];   // 33792 B
    __shared__ float nml[256];                          //  1024 B -> 44032 B total

    nml[tid] = nmask[b * 256 + tid];

    bf16x8 bm[4][2], ba[4][2], bw[8];
    const int cw = w * 64;
#pragma unroll
    for (int ct = 0; ct < 4; ++ct) {
        const int c = cw + ct * 16 + l16;
#pragma unroll
        for (int s = 0; s < 2; ++s) {
            bf16x8 t1, t2;
#pragma unroll
            for (int jj = 0; jj < 8; ++jj) {
                const int d = s * 32 + quad * 8 + jj;
                t1[jj] = f2bf(Wm[d * 256 + c]);
                t2[jj] = f2bf(Wa[d * 256 + c]);
            }
            bm[ct][s] = t1; ba[ct][s] = t2;
        }
    }
    const int cp = w * 16 + l16;
    {
#pragma unroll
        for (int s = 0; s < 8; ++s) {
            bf16x8 t;
#pragma unroll
            for (int jj = 0; jj < 8; ++jj) {
                const int cch = s * 32 + quad * 8 + jj;
                t[jj] = f2bf(We_out[cch * 64 + cp]);
            }
            bw[s] = t;
        }
    }
    const float bo = be_out[cp];

    const float rs = 0.17677669529663687f;
    float qc[4], ye1c[4], ye2c[4];
#pragma unroll
    for (int ct = 0; ct < 4; ++ct) {
        const int c = cw + ct * 16 + l16;
        qc[ct]   = ws[OFF_Q + (size_t)(b * 256 + i) * 256 + c] * rs;
        ye1c[ct] = ws[OFF_YE1 + b * 256 + c];
        ye2c[ct] = ws[OFF_YE2 + b * 256 + c] + 1.f;
    }
    const float* kTb = ws + OFF_K + (size_t)b * 65536;   // [c][j]
    const float* vTb = ws + OFF_V + (size_t)b * 65536;   // [c][j]

    const float* eb = e + ((size_t)(b * 256 + i)) * 256 * 64;
    const int jr = tid >> 3, c0 = (tid & 7) * 8;
    {
        float4 A = *(const float4*)(eb + jr * 64 + c0);
        float4 B = *(const float4*)(eb + jr * 64 + c0 + 4);
        pack8_store(A, B, &ebuf[0][jr * EBP + c0]);
    }
    __syncthreads();
    const float mi = nml[i];
    const size_t outbase = (size_t)(b * 256 + i) * 256;

    float msm[4], lsm[4], wsm[4];
#pragma unroll
    for (int ct = 0; ct < 4; ++ct) { msm[ct] = -1e30f; lsm[ct] = 0.f; wsm[ct] = 0.f; }

    for (int chunk = 0; chunk < 8; ++chunk) {
        const int cur = chunk & 1, j0 = chunk * 32;

        // e prefetch (HBM/L3) issued first — consumed at end of S1
        float4 pfA, pfB;
        if (chunk < 7) {
            const float* nb = eb + (size_t)(j0 + 32 + jr) * 64 + c0;
            pfA = *(const float4*)(nb);
            pfB = *(const float4*)(nb + 4);
        }

        bf16x8 ae[2][2];
#pragma unroll
        for (int jt = 0; jt < 2; ++jt)
#pragma unroll
            for (int s = 0; s < 2; ++s)
                ae[jt][s] = *(const bf16x8*)&ebuf[cur][(jt * 16 + l16) * EBP + s * 32 + quad * 8];

        float emv[8];
#pragma unroll
        for (int jt = 0; jt < 2; ++jt)
#pragma unroll
            for (int r = 0; r < 4; ++r)
                emv[jt * 4 + r] = mi * nml[j0 + jt * 16 + quad * 4 + r];

#pragma unroll
        for (int ct = 0; ct < 4; ++ct) {
            const int c = cw + ct * 16 + l16;

            // K/V from transposed layout: 4 float4 loads (vs 32 scalar loads)
            const float4 K0 = *(const float4*)&kTb[c * 256 + j0 + quad * 4];
            const float4 K1 = *(const float4*)&kTb[c * 256 + j0 + 16 + quad * 4];
            const float4 V0 = *(const float4*)&vTb[c * 256 + j0 + quad * 4];
            const float4 V1 = *(const float4*)&vTb[c * 256 + j0 + 16 + quad * 4];
            const float Ks[8] = {K0.x, K0.y, K0.z, K0.w, K1.x, K1.y, K1.z, K1.w};
            const float Vs[8] = {V0.x, V0.y, V0.z, V0.w, V1.x, V1.y, V1.z, V1.w};

            f32x4 a1_0 = {0.f, 0.f, 0.f, 0.f}, a1_1 = {0.f, 0.f, 0.f, 0.f};
            f32x4 a2_0 = {0.f, 0.f, 0.f, 0.f}, a2_1 = {0.f, 0.f, 0.f, 0.f};
#pragma unroll
            for (int s = 0; s < 2; ++s) {
                a1_0 = __builtin_amdgcn_mfma_f32_16x16x32_bf16(ae[0][s], bm[ct][s], a1_0, 0, 0, 0);
                a1_1 = __builtin_amdgcn_mfma_f32_16x16x32_bf16(ae[1][s], bm[ct][s], a1_1, 0, 0, 0);
                a2_0 = __builtin_amdgcn_mfma_f32_16x16x32_bf16(ae[0][s], ba[ct][s], a2_0, 0, 0, 0);
                a2_1 = __builtin_amdgcn_mfma_f32_16x16x32_bf16(ae[1][s], ba[ct][s], a2_1, 0, 0, 0);
            }

            float Ys[8];
#pragma unroll
            for (int jt = 0; jt < 2; ++jt) {
                float yv[4];
#pragma unroll
                for (int r = 0; r < 4; ++r) {
                    const int u  = jt * 4 + r;
                    const float e1v = (jt == 0) ? a1_0[r] : a1_1[r];
                    const float e2v = (jt == 0) ? a2_0[r] : a2_1[r];
                    const float em = emv[u];
                    const float Yv = fmaf(qc[ct] * Ks[u], fmaf(e1v, em, 1.f), e2v * em);
                    yv[r] = fmaf(ye2c[ct], Yv, ye1c[ct]);
                    Ys[u] = (em > 0.f) ? Yv : -1e9f;
                }
                const int jl0 = jt * 16 + quad * 4;
                unsigned short* yb = (unsigned short*)&ypl[cur][jl0 * YPLP + c];
                const unsigned p01 = cvt_pk_bf16(yv[0], yv[1]);
                const unsigned p23 = cvt_pk_bf16(yv[2], yv[3]);
                yb[0]        = (unsigned short)p01;
                yb[YPLP]     = (unsigned short)(p01 >> 16);
                yb[2 * YPLP] = (unsigned short)p23;
                yb[3 * YPLP] = (unsigned short)(p23 >> 16);
            }
            float cm = Ys[0];
#pragma unroll
            for (int u = 1; u < 8; ++u) cm = fmaxf(cm, Ys[u]);
            const float mnew = fmaxf(msm[ct], cm);
            const float al = __expf(msm[ct] - mnew);
            float sum = 0.f, wsum = 0.f;
#pragma unroll
            for (int u = 0; u < 8; ++u) {
                const float p = __expf(Ys[u] - mnew);
                sum += p; wsum = fmaf(p, Vs[u], wsum);
            }
            lsm[ct] = fmaf(lsm[ct], al, sum);
            wsm[ct] = fmaf(wsm[ct], al, wsum);
            msm[ct] = mnew;
        }

        if (chunk < 7) pack8_store(pfA, pfB, &ebuf[cur ^ 1][jr * EBP + c0]);
        __syncthreads();   // the ONLY barrier per chunk

        f32x4 acc0 = {0.f, 0.f, 0.f, 0.f}, acc1 = {0.f, 0.f, 0.f, 0.f};
#pragma unroll
        for (int s = 0; s < 8; ++s) {
            bf16x8 a0 = *(const bf16x8*)&ypl[cur][(l16) * YPLP + s * 32 + quad * 8];
            bf16x8 a1 = *(const bf16x8*)&ypl[cur][(16 + l16) * YPLP + s * 32 + quad * 8];
            acc0 = __builtin_amdgcn_mfma_f32_16x16x32_bf16(a0, bw[s], acc0, 0, 0, 0);
            acc1 = __builtin_amdgcn_mfma_f32_16x16x32_bf16(a1, bw[s], acc1, 0, 0, 0);
        }
#pragma unroll
        for (int jt = 0; jt < 2; ++jt)
#pragma unroll
            for (int r = 0; r < 4; ++r) {
                const int jl = jt * 16 + quad * 4 + r;
                const int jg = j0 + jl;
                const float em2 = mi * nml[jg];
                const float av = (jt == 0) ? acc0[r] : acc1[r];
                outE[(outbase + jg) * 64 + cp] = (av + bo) * em2;
            }
    }

#pragma unroll
    for (int ct = 0; ct < 4; ++ct) {
        float m = msm[ct], l = lsm[ct], wv = wsm[ct];
#pragma unroll
        for (int off = 16; off < 64; off <<= 1) {
            const float m2 = __shfl_xor(m, off, 64);
            const float l2 = __shfl_xor(l, off, 64);
            const float w2 = __shfl_xor(wv, off, 64);
            const float mn = fmaxf(m, m2);
            const float s1 = __expf(m - mn), s2 = __expf(m2 - mn);
            l = l * s1 + l2 * s2;
            wv = wv * s1 + w2 * s2;
            m = mn;
        }
        if (quad == 0) {
            const int c = cw + ct * 16 + l16;
            const float weighted = wv / l;
            const float yx1 = ws[OFF_YX1 + b * 256 + c];
            const float yx2 = ws[OFF_YX2 + b * 256 + c] + 1.f;
            xw[(size_t)(b * 256 + i) * 256 + c] = fmaf(yx2, weighted, yx1);
        }
    }
}

// ================= POST: rowgemm (64 blocks) + per-batch newY (4 blocks, k-split) =================
__global__ __launch_bounds__(256) void post_kernel(
    const float* __restrict__ xwin, const float* __restrict__ Wx_out,
    const float* __restrict__ bx_out, const float* __restrict__ nm,
    const float* __restrict__ y,
    const float* __restrict__ Wyy, const float* __restrict__ Wxy,
    const float* __restrict__ bxy, const float* __restrict__ Wey,
    const float* __restrict__ bey, const float* __restrict__ Wy_out,
    const float* __restrict__ by_out,
    const float* __restrict__ ws, float* __restrict__ outX, float* __restrict__ outY) {

    __shared__ float smem[16 * 256];
    const int blk = blockIdx.x;
    const int t = threadIdx.x;

    if (blk < 64) {
        const int m0 = blk * 16;
        float (*xl)[256] = (float(*)[256])smem;
        for (int r = 0; r < 16; ++r) xl[r][t] = xwin[(m0 + r) * 256 + t];
        __syncthreads();
        float acc[16];
#pragma unroll
        for (int r = 0; r < 16; ++r) acc[r] = 0.f;
        for (int d = 0; d < 256; d += 4) {
            float w0 = Wx_out[(d + 0) * 256 + t];
            float w1 = Wx_out[(d + 1) * 256 + t];
            float w2 = Wx_out[(d + 2) * 256 + t];
            float w3 = Wx_out[(d + 3) * 256 + t];
#pragma unroll
            for (int r = 0; r < 16; ++r) {
                float4 ev = *(const float4*)&xl[r][d];
                acc[r] = fmaf(ev.x, w0, fmaf(ev.y, w1, fmaf(ev.z, w2, fmaf(ev.w, w3, acc[r]))));
            }
        }
        const float bv = bx_out[t];
#pragma unroll
        for (int r = 0; r < 16; ++r) {
            int m = m0 + r;
            outX[m * 256 + t] = (acc[r] + bv) * nm[m];
        }
    } else {
        // one block per batch; 4-way k-split over threads
        const int b = blk - 64;
        const int d = t & 63, g = t >> 6;
        {
            float S = 0.f, Q = 0.f, Mn = 1e30f, Mx = -1e30f;
            for (int ss = g * 16; ss < g * 16 + 16; ++ss) {
                const float* ep = ws + OFF_EPART + ((b * 64 + ss) * 64 + d) * 4;
                float4 p = *(const float4*)ep;
                S += p.x; Q += p.y; Mn = fminf(Mn, p.z); Mx = fmaxf(Mx, p.w);
            }
            float (*red)[4][64] = (float(*)[4][64])smem;
            red[0][g][d] = S; red[1][g][d] = Q; red[2][g][d] = Mn; red[3][g][d] = Mx;
        }
        __syncthreads();
        float* pe = smem + 1024;
        if (g == 0) {
            float (*red)[4][64] = (float(*)[4][64])smem;
            float S = 0.f, Q = 0.f, Mn = 1e30f, Mx = -1e30f;
#pragma unroll
            for (int gg = 0; gg < 4; ++gg) {
                S += red[0][gg][d]; Q += red[1][gg][d];
                Mn = fminf(Mn, red[2][gg][d]); Mx = fmaxf(Mx, red[3][gg][d]);
            }
            const float n = 65536.f;
            float meane = S / n;
            float vare  = (Q - S * S / n) / (n - 1.f);
            vare = fmaxf(vare, 0.f);
            pe[d]       = meane;
            pe[64 + d]  = Mn;
            pe[128 + d] = Mx;
            pe[192 + d] = sqrtf(vare);
        }
        __syncthreads();
        const int o = t & 63, ks = t >> 6;
        float a = 0.f;
        if (ks == 0) {
            a = bxy[o] + bey[o];
            for (int k = 0; k < 64; ++k) a = fmaf(y[b * 64 + k], Wyy[k * 64 + o], a);
        }
        for (int k = ks * 64; k < ks * 64 + 64; ++k) a = fmaf(pe[k], Wey[k * 64 + o], a);
        const float* px = ws + OFF_PX + b * 1024;
        for (int k = ks * 256; k < ks * 256 + 256; ++k) a = fmaf(px[k], Wxy[k * 64 + o], a);
        float* redB = smem + 1280;
        redB[ks * 64 + o] = a;
        __syncthreads();
        float* sy = smem + 1536;
        if (ks == 0) sy[o] = redB[o] + redB[64 + o] + redB[128 + o] + redB[192 + o];
        __syncthreads();
        if (t < 64) {
            float r = by_out[t];
            for (int k = 0; k < 64; ++k) r = fmaf(sy[k], Wy_out[k * 64 + t], r);
            outY[b * 64 + t] = r;
        }
    }
}

extern "C" void kernel_launch(void* const* d_in, const int* in_sizes, int n_in,
                              void* d_out, int out_size, void* d_ws, size_t ws_size,
                              hipStream_t stream) {
    const float* x        = (const float*)d_in[0];
    const float* e        = (const float*)d_in[1];
    const float* y        = (const float*)d_in[2];
    const float* nm       = (const float*)d_in[3];
    const float* Wq       = (const float*)d_in[4];
    const float* Wk       = (const float*)d_in[5];
    const float* Wv       = (const float*)d_in[6];
    const float* We_mul   = (const float*)d_in[7];
    const float* We_add   = (const float*)d_in[8];
    const float* Wye_add  = (const float*)d_in[9];
    const float* Wye_mul  = (const float*)d_in[10];
    const float* Wyx_add  = (const float*)d_in[11];
    const float* Wyx_mul  = (const float*)d_in[12];
    const float* Wyy      = (const float*)d_in[13];
    const float* Wxy      = (const float*)d_in[14];
    const float* bxy      = (const float*)d_in[15];
    const float* Wey      = (const float*)d_in[16];
    const float* bey      = (const float*)d_in[17];
    const float* We_out   = (const float*)d_in[18];
    const float* be_out   = (const float*)d_in[19];
    const float* Wx_out   = (const float*)d_in[20];
    const float* bx_out   = (const float*)d_in[21];
    const float* Wy_out   = (const float*)d_in[22];
    const float* by_out   = (const float*)d_in[23];

    float* ws   = (float*)d_ws;
    float* outX = (float*)d_out;
    float* outE = (float*)d_out + 262144;
    float* outY = (float*)d_out + 262144 + 16777216;

    prep_kernel<<<456, 256, 0, stream>>>(x, e, y, nm, Wq, Wk, Wv,
                                         Wye_add, Wye_mul, Wyx_add, Wyx_mul, ws);
    fusedmfma_kernel<<<dim3(256, 4), 256, 0, stream>>>(e, nm, We_mul, We_add, We_out, be_out,
                                                       ws, outE, ws + OFF_XW);
    // 64 rowgemm blocks + 4 per-batch newY blocks (blk 64..67) => 68 blocks
    post_kernel<<<68, 256, 0, stream>>>(ws + OFF_XW, Wx_out, bx_out, nm, y,
                                        Wyy, Wxy, bxy, Wey, bey, Wy_out, by_out,
                                        ws, outX, outY);
}

// Round 10
// 268.182 us; speedup vs baseline: 1.3863x; 1.3863x over previous
//
#include <hip/hip_runtime.h>
#include <hip/hip_bf16.h>

#define BSZ 4
#define NN  256
#define DXX 256
#define DEE 64
#define DYY 64

// ---- workspace layout (float offsets) ----
#define OFF_Q     0          // 262144  (row-major [b][i][c])
#define OFF_K     262144     // 262144  (TRANSPOSED: [b][c][j])
#define OFF_V     524288     // 262144  (TRANSPOSED: [b][c][j])
#define OFF_XW    786432     // 262144
#define OFF_YE1   1048576    // 1024
#define OFF_YE2   1049600    // 1024
#define OFF_YX1   1050624    // 1024
#define OFF_YX2   1051648    // 1024
#define OFF_PX    1052672    // 4096
#define OFF_EPART 1057792    // 65536

typedef __attribute__((ext_vector_type(8))) short bf16x8;
typedef __attribute__((ext_vector_type(4))) float f32x4;

__device__ __forceinline__ short f2bf(float f) {
    unsigned u = __float_as_uint(f);
    unsigned r = u + 0x7fffu + ((u >> 16) & 1u);
    return (short)(r >> 16);
}

// packed f32x2 -> bf16x2 (RTNE), 1 VALU op per 2 values (no builtin on gfx950)
__device__ __forceinline__ unsigned cvt_pk_bf16(float lo, float hi) {
    unsigned r;
    asm("v_cvt_pk_bf16_f32 %0, %1, %2" : "=v"(r) : "v"(lo), "v"(hi));
    return r;
}

__device__ __forceinline__ void pack8_store(const float4& A, const float4& B, short* dst) {
    uint4 v;
    v.x = cvt_pk_bf16(A.x, A.y);
    v.y = cvt_pk_bf16(A.z, A.w);
    v.z = cvt_pk_bf16(B.x, B.y);
    v.w = cvt_pk_bf16(B.z, B.w);
    *(uint4*)dst = v;
}

// ===== PREP: qkv 8-row blocks (384) + yproj (4) + epoolA (256) + xpool (4) = 648 blocks =====
// R9: qkv split 16->8 rows/block (192->384 blocks) to balance the 648-block 2-wave schedule.
__global__ __launch_bounds__(256) void prep_kernel(
    const float* __restrict__ x, const float* __restrict__ e, const float* __restrict__ y,
    const float* __restrict__ nm,
    const float* __restrict__ Wq, const float* __restrict__ Wk, const float* __restrict__ Wv,
    const float* __restrict__ Wye_add, const float* __restrict__ Wye_mul,
    const float* __restrict__ Wyx_add, const float* __restrict__ Wyx_mul,
    float* __restrict__ ws) {

    __shared__ float smem[16 * 256];
    const int blk = blockIdx.x;
    const int t = threadIdx.x;

    if (blk < 384) {
        const int which = blk >> 7;          // 128 row-blocks per W
        const int m0 = (blk & 127) * 8;      // 8 rows per block
        const float* W = which == 0 ? Wq : (which == 1 ? Wk : Wv);
        float* out = ws + (size_t)which * 262144;
        float (*xl)[256] = (float(*)[256])smem;
        for (int r = 0; r < 8; ++r) xl[r][t] = x[(m0 + r) * 256 + t];
        __syncthreads();
        float acc[8];
#pragma unroll
        for (int r = 0; r < 8; ++r) acc[r] = 0.f;
        for (int d = 0; d < 256; d += 4) {
            float w0 = W[(d + 0) * 256 + t];
            float w1 = W[(d + 1) * 256 + t];
            float w2 = W[(d + 2) * 256 + t];
            float w3 = W[(d + 3) * 256 + t];
#pragma unroll
            for (int r = 0; r < 8; ++r) {
                float4 ev = *(const float4*)&xl[r][d];
                acc[r] = fmaf(ev.x, w0, fmaf(ev.y, w1, fmaf(ev.z, w2, fmaf(ev.w, w3, acc[r]))));
            }
        }
        if (which == 0) {
            // Q stays row-major [b][i][c]
#pragma unroll
            for (int r = 0; r < 8; ++r) {
                int m = m0 + r;
                out[m * 256 + t] = acc[r] * nm[m];
            }
        } else {
            // K,V stored TRANSPOSED [b][c][j]; m0 = b*256 + jloc (8 rows never straddle a batch)
            const int bb2  = m0 >> 8;
            const int jloc = m0 & 255;
            float tv[8];
#pragma unroll
            for (int r = 0; r < 8; ++r) tv[r] = acc[r] * nm[m0 + r];
            float* outb = out + (size_t)bb2 * 65536 + t * 256 + jloc;
            *(float4*)&outb[0] = make_float4(tv[0], tv[1], tv[2], tv[3]);
            *(float4*)&outb[4] = make_float4(tv[4], tv[5], tv[6], tv[7]);
        }
    } else if (blk < 388) {
        const int b = blk - 384;
        float a1 = 0.f, a2 = 0.f, a3 = 0.f, a4 = 0.f;
        for (int k = 0; k < DYY; ++k) {
            float yv = y[b * DYY + k];
            a1 = fmaf(yv, Wye_add[k * 256 + t], a1);
            a2 = fmaf(yv, Wye_mul[k * 256 + t], a2);
            a3 = fmaf(yv, Wyx_add[k * 256 + t], a3);
            a4 = fmaf(yv, Wyx_mul[k * 256 + t], a4);
        }
        ws[OFF_YE1 + b * 256 + t] = a1;
        ws[OFF_YE2 + b * 256 + t] = a2;
        ws[OFF_YX1 + b * 256 + t] = a3;
        ws[OFF_YX2 + b * 256 + t] = a4;
    } else if (blk < 644) {
        // e-pool partials: float4 loads
        const int idx = blk - 388;
        const int s = idx & 63, bb = idx >> 6;
        const int dq = (t & 15) * 4, g = t >> 4;
        const float* base = e + ((size_t)bb * 65536 + s * 1024) * 64;
        float s0 = 0.f, s1 = 0.f, s2 = 0.f, s3 = 0.f;
        float q0 = 0.f, q1 = 0.f, q2 = 0.f, q3 = 0.f;
        float mn0 = 1e30f, mn1 = 1e30f, mn2 = 1e30f, mn3 = 1e30f;
        float mx0 = -1e30f, mx1 = -1e30f, mx2 = -1e30f, mx3 = -1e30f;
#pragma unroll 4
        for (int rr = 0; rr < 64; ++rr) {
            const int row = g * 64 + rr;
            float4 v = *(const float4*)&base[row * 64 + dq];
            s0 += v.x; s1 += v.y; s2 += v.z; s3 += v.w;
            q0 = fmaf(v.x, v.x, q0); q1 = fmaf(v.y, v.y, q1);
            q2 = fmaf(v.z, v.z, q2); q3 = fmaf(v.w, v.w, q3);
            mn0 = fminf(mn0, v.x); mn1 = fminf(mn1, v.y);
            mn2 = fminf(mn2, v.z); mn3 = fminf(mn3, v.w);
            mx0 = fmaxf(mx0, v.x); mx1 = fmaxf(mx1, v.y);
            mx2 = fmaxf(mx2, v.z); mx3 = fmaxf(mx3, v.w);
        }
        float (*red)[16][64] = (float(*)[16][64])smem;
        red[0][g][dq + 0] = s0;  red[0][g][dq + 1] = s1;  red[0][g][dq + 2] = s2;  red[0][g][dq + 3] = s3;
        red[1][g][dq + 0] = q0;  red[1][g][dq + 1] = q1;  red[1][g][dq + 2] = q2;  red[1][g][dq + 3] = q3;
        red[2][g][dq + 0] = mn0; red[2][g][dq + 1] = mn1; red[2][g][dq + 2] = mn2; red[2][g][dq + 3] = mn3;
        red[3][g][dq + 0] = mx0; red[3][g][dq + 1] = mx1; red[3][g][dq + 2] = mx2; red[3][g][dq + 3] = mx3;
        __syncthreads();
        const int stat = t >> 6, d = t & 63;
        float a;
        if (stat < 2) {
            a = 0.f;
            for (int gg = 0; gg < 16; ++gg) a += red[stat][gg][d];
        } else if (stat == 2) {
            a = 1e30f;
            for (int gg = 0; gg < 16; ++gg) a = fminf(a, red[2][gg][d]);
        } else {
            a = -1e30f;
            for (int gg = 0; gg < 16; ++gg) a = fmaxf(a, red[3][gg][d]);
        }
        ws[OFF_EPART + (size_t)((bb * 64 + s) * 64 + d) * 4 + stat] = a;
    } else {
        const int b = blk - 644;
        float s = 0.f, q = 0.f, mn = 1e30f, mx = -1e30f;
        for (int i = 0; i < 256; ++i) {
            float v = x[(b * 256 + i) * 256 + t];
            s += v; q = fmaf(v, v, q);
            mn = fminf(mn, v); mx = fmaxf(mx, v);
        }
        float mean = s * (1.f / 256.f);
        float var  = (q - s * s * (1.f / 256.f)) * (1.f / 255.f);
        var = fmaxf(var, 0.f);
        ws[OFF_PX + b * 1024 + t]       = mean;
        ws[OFF_PX + b * 1024 + 256 + t] = mn;
        ws[OFF_PX + b * 1024 + 512 + t] = mx;
        ws[OFF_PX + b * 1024 + 768 + t] = sqrtf(var);
    }
}

// ================= FUSED: E1/E2 (MFMA) + Y + online softmax + newE (MFMA) + xw =================
// ONE barrier per chunk (see R7). KEEP __launch_bounds__(256,2): R8 measured that (256,3)
// forces VGPR 112->84, spilling the weight frags (FETCH 43->190 MB, dur 95.6->177 us).
// Register demand incl. AGPRs does not fit 3 waves/SIMD — do not retry.
#define EBP  72
#define YPLP 264

__global__ __launch_bounds__(256, 2) void fusedmfma_kernel(
    const float* __restrict__ e, const float* __restrict__ nmask,
    const float* __restrict__ Wm, const float* __restrict__ Wa,
    const float* __restrict__ We_out, const float* __restrict__ be_out,
    const float* __restrict__ ws, float* __restrict__ outE, float* __restrict__ xw) {

    const int i = blockIdx.x, b = blockIdx.y;
    const int tid  = threadIdx.x;
    const int w    = tid >> 6;
    const int lane = tid & 63;
    const int quad = lane >> 4, l16 = lane & 15;

    __shared__ __align__(16) short ebuf[2][32 * EBP];   //  9216 B
    __shared__ __align__(16) short ypl[2][32 * YPLP];   // 33792 B
    __shared__ float nml[256];                          //  1024 B -> 44032 B total

    nml[tid] = nmask[b * 256 + tid];

    bf16x8 bm[4][2], ba[4][2], bw[8];
    const int cw = w * 64;
#pragma unroll
    for (int ct = 0; ct < 4; ++ct) {
        const int c = cw + ct * 16 + l16;
#pragma unroll
        for (int s = 0; s < 2; ++s) {
            bf16x8 t1, t2;
#pragma unroll
            for (int jj = 0; jj < 8; ++jj) {
                const int d = s * 32 + quad * 8 + jj;
                t1[jj] = f2bf(Wm[d * 256 + c]);
                t2[jj] = f2bf(Wa[d * 256 + c]);
            }
            bm[ct][s] = t1; ba[ct][s] = t2;
        }
    }
    const int cp = w * 16 + l16;
    {
#pragma unroll
        for (int s = 0; s < 8; ++s) {
            bf16x8 t;
#pragma unroll
            for (int jj = 0; jj < 8; ++jj) {
                const int cch = s * 32 + quad * 8 + jj;
                t[jj] = f2bf(We_out[cch * 64 + cp]);
            }
            bw[s] = t;
        }
    }
    const float bo = be_out[cp];

    const float rs = 0.17677669529663687f;
    float qc[4], ye1c[4], ye2c[4];
#pragma unroll
    for (int ct = 0; ct < 4; ++ct) {
        const int c = cw + ct * 16 + l16;
        qc[ct]   = ws[OFF_Q + (size_t)(b * 256 + i) * 256 + c] * rs;
        ye1c[ct] = ws[OFF_YE1 + b * 256 + c];
        ye2c[ct] = ws[OFF_YE2 + b * 256 + c] + 1.f;
    }
    const float* kTb = ws + OFF_K + (size_t)b * 65536;   // [c][j]
    const float* vTb = ws + OFF_V + (size_t)b * 65536;   // [c][j]

    const float* eb = e + ((size_t)(b * 256 + i)) * 256 * 64;
    const int jr = tid >> 3, c0 = (tid & 7) * 8;
    {
        float4 A = *(const float4*)(eb + jr * 64 + c0);
        float4 B = *(const float4*)(eb + jr * 64 + c0 + 4);
        pack8_store(A, B, &ebuf[0][jr * EBP + c0]);
    }
    __syncthreads();
    const float mi = nml[i];
    const size_t outbase = (size_t)(b * 256 + i) * 256;

    float msm[4], lsm[4], wsm[4];
#pragma unroll
    for (int ct = 0; ct < 4; ++ct) { msm[ct] = -1e30f; lsm[ct] = 0.f; wsm[ct] = 0.f; }

    for (int chunk = 0; chunk < 8; ++chunk) {
        const int cur = chunk & 1, j0 = chunk * 32;

        // e prefetch (HBM/L3) issued first — consumed at end of S1
        float4 pfA, pfB;
        if (chunk < 7) {
            const float* nb = eb + (size_t)(j0 + 32 + jr) * 64 + c0;
            pfA = *(const float4*)(nb);
            pfB = *(const float4*)(nb + 4);
        }

        bf16x8 ae[2][2];
#pragma unroll
        for (int jt = 0; jt < 2; ++jt)
#pragma unroll
            for (int s = 0; s < 2; ++s)
                ae[jt][s] = *(const bf16x8*)&ebuf[cur][(jt * 16 + l16) * EBP + s * 32 + quad * 8];

        float emv[8];
#pragma unroll
        for (int jt = 0; jt < 2; ++jt)
#pragma unroll
            for (int r = 0; r < 4; ++r)
                emv[jt * 4 + r] = mi * nml[j0 + jt * 16 + quad * 4 + r];

#pragma unroll
        for (int ct = 0; ct < 4; ++ct) {
            const int c = cw + ct * 16 + l16;

            // K/V from transposed layout: 4 float4 loads (vs 32 scalar loads)
            const float4 K0 = *(const float4*)&kTb[c * 256 + j0 + quad * 4];
            const float4 K1 = *(const float4*)&kTb[c * 256 + j0 + 16 + quad * 4];
            const float4 V0 = *(const float4*)&vTb[c * 256 + j0 + quad * 4];
            const float4 V1 = *(const float4*)&vTb[c * 256 + j0 + 16 + quad * 4];
            const float Ks[8] = {K0.x, K0.y, K0.z, K0.w, K1.x, K1.y, K1.z, K1.w};
            const float Vs[8] = {V0.x, V0.y, V0.z, V0.w, V1.x, V1.y, V1.z, V1.w};

            f32x4 a1_0 = {0.f, 0.f, 0.f, 0.f}, a1_1 = {0.f, 0.f, 0.f, 0.f};
            f32x4 a2_0 = {0.f, 0.f, 0.f, 0.f}, a2_1 = {0.f, 0.f, 0.f, 0.f};
#pragma unroll
            for (int s = 0; s < 2; ++s) {
                a1_0 = __builtin_amdgcn_mfma_f32_16x16x32_bf16(ae[0][s], bm[ct][s], a1_0, 0, 0, 0);
                a1_1 = __builtin_amdgcn_mfma_f32_16x16x32_bf16(ae[1][s], bm[ct][s], a1_1, 0, 0, 0);
                a2_0 = __builtin_amdgcn_mfma_f32_16x16x32_bf16(ae[0][s], ba[ct][s], a2_0, 0, 0, 0);
                a2_1 = __builtin_amdgcn_mfma_f32_16x16x32_bf16(ae[1][s], ba[ct][s], a2_1, 0, 0, 0);
            }

            float Ys[8];
#pragma unroll
            for (int jt = 0; jt < 2; ++jt) {
                float yv[4];
#pragma unroll
                for (int r = 0; r < 4; ++r) {
                    const int u  = jt * 4 + r;
                    const float e1v = (jt == 0) ? a1_0[r] : a1_1[r];
                    const float e2v = (jt == 0) ? a2_0[r] : a2_1[r];
                    const float em = emv[u];
                    const float Yv = fmaf(qc[ct] * Ks[u], fmaf(e1v, em, 1.f), e2v * em);
                    yv[r] = fmaf(ye2c[ct], Yv, ye1c[ct]);
                    Ys[u] = (em > 0.f) ? Yv : -1e9f;
                }
                const int jl0 = jt * 16 + quad * 4;
                unsigned short* yb = (unsigned short*)&ypl[cur][jl0 * YPLP + c];
                const unsigned p01 = cvt_pk_bf16(yv[0], yv[1]);
                const unsigned p23 = cvt_pk_bf16(yv[2], yv[3]);
                yb[0]        = (unsigned short)p01;
                yb[YPLP]     = (unsigned short)(p01 >> 16);
                yb[2 * YPLP] = (unsigned short)p23;
                yb[3 * YPLP] = (unsigned short)(p23 >> 16);
            }
            float cm = Ys[0];
#pragma unroll
            for (int u = 1; u < 8; ++u) cm = fmaxf(cm, Ys[u]);
            const float mnew = fmaxf(msm[ct], cm);
            const float al = __expf(msm[ct] - mnew);
            float sum = 0.f, wsum = 0.f;
#pragma unroll
            for (int u = 0; u < 8; ++u) {
                const float p = __expf(Ys[u] - mnew);
                sum += p; wsum = fmaf(p, Vs[u], wsum);
            }
            lsm[ct] = fmaf(lsm[ct], al, sum);
            wsm[ct] = fmaf(wsm[ct], al, wsum);
            msm[ct] = mnew;
        }

        if (chunk < 7) pack8_store(pfA, pfB, &ebuf[cur ^ 1][jr * EBP + c0]);
        __syncthreads();   // the ONLY barrier per chunk

        f32x4 acc0 = {0.f, 0.f, 0.f, 0.f}, acc1 = {0.f, 0.f, 0.f, 0.f};
#pragma unroll
        for (int s = 0; s < 8; ++s) {
            bf16x8 a0 = *(const bf16x8*)&ypl[cur][(l16) * YPLP + s * 32 + quad * 8];
            bf16x8 a1 = *(const bf16x8*)&ypl[cur][(16 + l16) * YPLP + s * 32 + quad * 8];
            acc0 = __builtin_amdgcn_mfma_f32_16x16x32_bf16(a0, bw[s], acc0, 0, 0, 0);
            acc1 = __builtin_amdgcn_mfma_f32_16x16x32_bf16(a1, bw[s], acc1, 0, 0, 0);
        }
#pragma unroll
        for (int jt = 0; jt < 2; ++jt)
#pragma unroll
            for (int r = 0; r < 4; ++r) {
                const int jl = jt * 16 + quad * 4 + r;
                const int jg = j0 + jl;
                const float em2 = mi * nml[jg];
                const float av = (jt == 0) ? acc0[r] : acc1[r];
                outE[(outbase + jg) * 64 + cp] = (av + bo) * em2;
            }
    }

#pragma unroll
    for (int ct = 0; ct < 4; ++ct) {
        float m = msm[ct], l = lsm[ct], wv = wsm[ct];
#pragma unroll
        for (int off = 16; off < 64; off <<= 1) {
            const float m2 = __shfl_xor(m, off, 64);
            const float l2 = __shfl_xor(l, off, 64);
            const float w2 = __shfl_xor(wv, off, 64);
            const float mn = fmaxf(m, m2);
            const float s1 = __expf(m - mn), s2 = __expf(m2 - mn);
            l = l * s1 + l2 * s2;
            wv = wv * s1 + w2 * s2;
            m = mn;
        }
        if (quad == 0) {
            const int c = cw + ct * 16 + l16;
            const float weighted = wv / l;
            const float yx1 = ws[OFF_YX1 + b * 256 + c];
            const float yx2 = ws[OFF_YX2 + b * 256 + c] + 1.f;
            xw[(size_t)(b * 256 + i) * 256 + c] = fmaf(yx2, weighted, yx1);
        }
    }
}

// ========== POST: rowgemm 8-row blocks (128) + per-batch newY (4 blocks) = 132 blocks ==========
// R9: rowgemm split 16->8 rows/block (64->128 blocks) — 64 blocks covered only 25% of CUs.
__global__ __launch_bounds__(256) void post_kernel(
    const float* __restrict__ xwin, const float* __restrict__ Wx_out,
    const float* __restrict__ bx_out, const float* __restrict__ nm,
    const float* __restrict__ y,
    const float* __restrict__ Wyy, const float* __restrict__ Wxy,
    const float* __restrict__ bxy, const float* __restrict__ Wey,
    const float* __restrict__ bey, const float* __restrict__ Wy_out,
    const float* __restrict__ by_out,
    const float* __restrict__ ws, float* __restrict__ outX, float* __restrict__ outY) {

    __shared__ float smem[16 * 256];
    const int blk = blockIdx.x;
    const int t = threadIdx.x;

    if (blk < 128) {
        const int m0 = blk * 8;
        float (*xl)[256] = (float(*)[256])smem;
        for (int r = 0; r < 8; ++r) xl[r][t] = xwin[(m0 + r) * 256 + t];
        __syncthreads();
        float acc[8];
#pragma unroll
        for (int r = 0; r < 8; ++r) acc[r] = 0.f;
        for (int d = 0; d < 256; d += 4) {
            float w0 = Wx_out[(d + 0) * 256 + t];
            float w1 = Wx_out[(d + 1) * 256 + t];
            float w2 = Wx_out[(d + 2) * 256 + t];
            float w3 = Wx_out[(d + 3) * 256 + t];
#pragma unroll
            for (int r = 0; r < 8; ++r) {
                float4 ev = *(const float4*)&xl[r][d];
                acc[r] = fmaf(ev.x, w0, fmaf(ev.y, w1, fmaf(ev.z, w2, fmaf(ev.w, w3, acc[r]))));
            }
        }
        const float bv = bx_out[t];
#pragma unroll
        for (int r = 0; r < 8; ++r) {
            int m = m0 + r;
            outX[m * 256 + t] = (acc[r] + bv) * nm[m];
        }
    } else {
        // one block per batch; 4-way k-split over threads
        const int b = blk - 128;
        const int d = t & 63, g = t >> 6;
        {
            float S = 0.f, Q = 0.f, Mn = 1e30f, Mx = -1e30f;
            for (int ss = g * 16; ss < g * 16 + 16; ++ss) {
                const float* ep = ws + OFF_EPART + ((b * 64 + ss) * 64 + d) * 4;
                float4 p = *(const float4*)ep;
                S += p.x; Q += p.y; Mn = fminf(Mn, p.z); Mx = fmaxf(Mx, p.w);
            }
            float (*red)[4][64] = (float(*)[4][64])smem;
            red[0][g][d] = S; red[1][g][d] = Q; red[2][g][d] = Mn; red[3][g][d] = Mx;
        }
        __syncthreads();
        float* pe = smem + 1024;
        if (g == 0) {
            float (*red)[4][64] = (float(*)[4][64])smem;
            float S = 0.f, Q = 0.f, Mn = 1e30f, Mx = -1e30f;
#pragma unroll
            for (int gg = 0; gg < 4; ++gg) {
                S += red[0][gg][d]; Q += red[1][gg][d];
                Mn = fminf(Mn, red[2][gg][d]); Mx = fmaxf(Mx, red[3][gg][d]);
            }
            const float n = 65536.f;
            float meane = S / n;
            float vare  = (Q - S * S / n) / (n - 1.f);
            vare = fmaxf(vare, 0.f);
            pe[d]       = meane;
            pe[64 + d]  = Mn;
            pe[128 + d] = Mx;
            pe[192 + d] = sqrtf(vare);
        }
        __syncthreads();
        const int o = t & 63, ks = t >> 6;
        float a = 0.f;
        if (ks == 0) {
            a = bxy[o] + bey[o];
            for (int k = 0; k < 64; ++k) a = fmaf(y[b * 64 + k], Wyy[k * 64 + o], a);
        }
        for (int k = ks * 64; k < ks * 64 + 64; ++k) a = fmaf(pe[k], Wey[k * 64 + o], a);
        const float* px = ws + OFF_PX + b * 1024;
        for (int k = ks * 256; k < ks * 256 + 256; ++k) a = fmaf(px[k], Wxy[k * 64 + o], a);
        float* redB = smem + 1280;
        redB[ks * 64 + o] = a;
        __syncthreads();
        float* sy = smem + 1536;
        if (ks == 0) sy[o] = redB[o] + redB[64 + o] + redB[128 + o] + redB[192 + o];
        __syncthreads();
        if (t < 64) {
            float r = by_out[t];
            for (int k = 0; k < 64; ++k) r = fmaf(sy[k], Wy_out[k * 64 + t], r);
            outY[b * 64 + t] = r;
        }
    }
}

extern "C" void kernel_launch(void* const* d_in, const int* in_sizes, int n_in,
                              void* d_out, int out_size, void* d_ws, size_t ws_size,
                              hipStream_t stream) {
    const float* x        = (const float*)d_in[0];
    const float* e        = (const float*)d_in[1];
    const float* y        = (const float*)d_in[2];
    const float* nm       = (const float*)d_in[3];
    const float* Wq       = (const float*)d_in[4];
    const float* Wk       = (const float*)d_in[5];
    const float* Wv       = (const float*)d_in[6];
    const float* We_mul   = (const float*)d_in[7];
    const float* We_add   = (const float*)d_in[8];
    const float* Wye_add  = (const float*)d_in[9];
    const float* Wye_mul  = (const float*)d_in[10];
    const float* Wyx_add  = (const float*)d_in[11];
    const float* Wyx_mul  = (const float*)d_in[12];
    const float* Wyy      = (const float*)d_in[13];
    const float* Wxy      = (const float*)d_in[14];
    const float* bxy      = (const float*)d_in[15];
    const float* Wey      = (const float*)d_in[16];
    const float* bey      = (const float*)d_in[17];
    const float* We_out   = (const float*)d_in[18];
    const float* be_out   = (const float*)d_in[19];
    const float* Wx_out   = (const float*)d_in[20];
    const float* bx_out   = (const float*)d_in[21];
    const float* Wy_out   = (const float*)d_in[22];
    const float* by_out   = (const float*)d_in[23];

    float* ws   = (float*)d_ws;
    float* outX = (float*)d_out;
    float* outE = (float*)d_out + 262144;
    float* outY = (float*)d_out + 262144 + 16777216;

    prep_kernel<<<648, 256, 0, stream>>>(x, e, y, nm, Wq, Wk, Wv,
                                         Wye_add, Wye_mul, Wyx_add, Wyx_mul, ws);
    fusedmfma_kernel<<<dim3(256, 4), 256, 0, stream>>>(e, nm, We_mul, We_add, We_out, be_out,
                                                       ws, outE, ws + OFF_XW);
    // 128 rowgemm blocks + 4 per-batch newY blocks (blk 128..131) => 132 blocks
    post_kernel<<<132, 256, 0, stream>>>(ws + OFF_XW, Wx_out, bx_out, nm, y,
                                         Wyy, Wxy, bxy, Wey, bey, Wy_out, by_out,
                                         ws, outX, outY);
}